// Round 8
// baseline (424.643 us; speedup 1.0000x reference)
//
#include <hip/hip_runtime.h>

#define DIM    512
#define CH     32
#define KDIM   16384   // CH*DIM
#define BATCH  2048
#define NOUT   512     // projection output dim
#define PWN    (NOUT * KDIM)   // proj_w elements: 8,388,608
#define CONVBLK (PWN / 4 / 256)  // 8192 blocks for the convert half

#define BM 128
#define BN 128
#define BK 64
#define KSPLIT 8
#define KC (KDIM / KSPLIT)   // 2048

typedef short bf16x8 __attribute__((ext_vector_type(8)));
typedef float f32x4  __attribute__((ext_vector_type(4)));

__device__ __forceinline__ float b2f(unsigned short u) {
    union { unsigned int i; float f; } v; v.i = ((unsigned int)u) << 16; return v.f;
}
__device__ __forceinline__ unsigned short f2b(float f) {
    union { float f; unsigned int i; } v; v.f = f;
    unsigned int r = v.i + 0x7fffu + ((v.i >> 16) & 1u);
    return (unsigned short)(r >> 16);
}
// dtype-flag load: isf=1 -> float32 array, isf=0 -> bf16 array
__device__ __forceinline__ float ldv(const void* p, size_t i, int isf) {
    return isf ? ((const float*)p)[i] : b2f(((const unsigned short*)p)[i]);
}
// In-wave dtype sniff on ent: f32 mantissa halfwords look random (~5% hit in
// the bf16-exponent window), bf16 halfwords land in it nearly always.
__device__ __forceinline__ int sniff_isf32(const unsigned short* ent_raw) {
    int lane = threadIdx.x & 63;
    unsigned short u = ent_raw[2 * lane];
    int eb = (u >> 8) & 0x7F;
    unsigned long long m = __ballot(eb >= 0x36 && eb < 0x3C);
    return (__popcll(m) < 32) ? 1 : 0;
}

__device__ __forceinline__ void gload_lds16(const unsigned short* g, unsigned short* l) {
    __builtin_amdgcn_global_load_lds(
        (const __attribute__((address_space(1))) void*)g,
        (__attribute__((address_space(3))) void*)l,
        16, 0, 0);
}

// ---------------------------------------------------------------------------
// Fused prep: blocks [0, CONVBLK) convert proj_w -> bf16 pw16;
// blocks [CONVBLK, CONVBLK+BATCH) build feat.
// feat[b, c*512+i] = relu(conv(concat(ent[h], rel[r]))[c, i] + cb[c]);
// SAME-pad k=3 cross-correlation truncated to i in [0,512): needs ent[h]
// (x[0..511]) and rel[r][0] (x[512]); left pad x[-1]=0.
// ---------------------------------------------------------------------------
__global__ __launch_bounds__(256) void prep_kernel(
    const int* __restrict__ h, const int* __restrict__ r,
    const void* __restrict__ ent, const void* __restrict__ rel,
    const void* __restrict__ conv_w, const void* __restrict__ conv_b,
    const void* __restrict__ projw,
    unsigned short* __restrict__ pw16, unsigned short* __restrict__ feat)
{
    const int tid = threadIdx.x;
    const int isf = sniff_isf32((const unsigned short*)ent);

    if (blockIdx.x < CONVBLK) {
        size_t i0 = ((size_t)blockIdx.x * 256 + tid) * 4;
        if (isf) {
            f32x4 v = *(const f32x4*)((const float*)projw + i0);
            unsigned int p0 = (unsigned int)f2b(v[0]) | ((unsigned int)f2b(v[1]) << 16);
            unsigned int p1 = (unsigned int)f2b(v[2]) | ((unsigned int)f2b(v[3]) << 16);
            *(unsigned int*)(pw16 + i0) = p0;
            *(unsigned int*)(pw16 + i0 + 2) = p1;
        } else {
            *(unsigned long long*)(pw16 + i0) =
                *(const unsigned long long*)((const unsigned short*)projw + i0);
        }
        return;
    }

    __shared__ float xs[DIM + 2];      // xs[0]=0 pad, xs[1..512]=h_e, xs[513]=r_e[0]
    __shared__ float wS[CH][4];
    const int b = blockIdx.x - CONVBLK;

    const size_t hb = (size_t)h[b] * DIM;
    for (int j = tid; j < DIM; j += 256) xs[1 + j] = ldv(ent, hb + j, isf);
    if (tid == 0) xs[0] = 0.0f;
    if (tid == 1) xs[DIM + 1] = ldv(rel, (size_t)r[b] * DIM, isf);
    if (tid >= 64 && tid < 96) {
        int c = tid - 64;
        wS[c][0] = ldv(conv_w, c * 3 + 0, isf);
        wS[c][1] = ldv(conv_w, c * 3 + 1, isf);
        wS[c][2] = ldv(conv_w, c * 3 + 2, isf);
        wS[c][3] = ldv(conv_b, c, isf);
    }
    __syncthreads();

    unsigned short* fb = feat + (size_t)b * KDIM;
    const int i0 = tid * 2;            // 2 adjacent outputs per channel
    float x0 = xs[i0], x1 = xs[i0 + 1], x2 = xs[i0 + 2], x3 = xs[i0 + 3];
    #pragma unroll 8
    for (int c = 0; c < CH; ++c) {
        float w0 = wS[c][0], w1 = wS[c][1], w2 = wS[c][2], cb = wS[c][3];
        float v0 = fmaxf(fmaf(w0, x0, fmaf(w1, x1, fmaf(w2, x2, cb))), 0.0f);
        float v1 = fmaxf(fmaf(w0, x1, fmaf(w1, x2, fmaf(w2, x3, cb))), 0.0f);
        unsigned int pack = (unsigned int)f2b(v0) | ((unsigned int)f2b(v1) << 16);
        *(unsigned int*)&fb[c * DIM + i0] = pack;
    }
}

// ---------------------------------------------------------------------------
// Xp[bz][m][n] = sum_{k slice bz} feat[m,k] * pw16[n,k]   (bf16 MFMA gemm_bt)
// M=2048 N=512 K=16384; 128x128 tile, BK=64, split-K=8 -> 512 blocks (2/CU).
// Async global_load_lds width-16; LDS dst byte offset = 1024*wave + 16*lane
// -> wave-uniform base + lane*16 (the G-L-LDS addressing rule).
// ---------------------------------------------------------------------------
__global__ __launch_bounds__(256, 2) void gemm_kernel(
    const unsigned short* __restrict__ feat,
    const unsigned short* __restrict__ pw16,
    float* __restrict__ Xp)
{
    __shared__ __align__(16) unsigned short As[BM * BK];   // 16 KB
    __shared__ __align__(16) unsigned short Bs[BN * BK];   // 16 KB

    const int tid  = threadIdx.x;
    const int lane = tid & 63;
    const int wave = tid >> 6;
    const int wm = wave & 1;         // 2x2 wave grid, each wave 64x64
    const int wn = wave >> 1;
    const int bx = blockIdx.x, by = blockIdx.y, bz = blockIdx.z;

    const unsigned short* Ab = feat + (size_t)(bx * BM) * KDIM + bz * KC;
    const unsigned short* Bb = pw16 + (size_t)(by * BN) * KDIM + bz * KC;

    const int row_ld = tid >> 3;         // 0..31
    const int koff   = (tid & 7) * 8;    // 8 bf16 = 16 B per lane

    const f32x4 zero = {0.f, 0.f, 0.f, 0.f};
    f32x4 acc[4][4];
    #pragma unroll
    for (int i = 0; i < 4; ++i)
        #pragma unroll
        for (int j = 0; j < 4; ++j) acc[i][j] = zero;

    const int fRow = lane & 15;          // operand row within 16
    const int fK   = (lane >> 4) * 8;    // k start within each 32-chunk

    for (int kk = 0; kk < KC; kk += BK) {
        #pragma unroll
        for (int j = 0; j < 4; ++j) {
            int rw = row_ld + 32 * j;
            gload_lds16(Ab + (size_t)rw * KDIM + kk + koff, As + rw * BK + koff);
            gload_lds16(Bb + (size_t)rw * KDIM + kk + koff, Bs + rw * BK + koff);
        }
        __syncthreads();   // drains vmcnt: staged data visible

        #pragma unroll
        for (int ko = 0; ko < 2; ++ko) {
            bf16x8 af[4], bfr[4];
            #pragma unroll
            for (int mi = 0; mi < 4; ++mi)
                af[mi] = *(const bf16x8*)&As[(wm * 64 + mi * 16 + fRow) * BK + ko * 32 + fK];
            #pragma unroll
            for (int ni = 0; ni < 4; ++ni)
                bfr[ni] = *(const bf16x8*)&Bs[(wn * 64 + ni * 16 + fRow) * BK + ko * 32 + fK];
            #pragma unroll
            for (int mi = 0; mi < 4; ++mi)
                #pragma unroll
                for (int ni = 0; ni < 4; ++ni)
                    acc[mi][ni] = __builtin_amdgcn_mfma_f32_16x16x32_bf16(
                        af[mi], bfr[ni], acc[mi][ni], 0, 0, 0);
        }
        __syncthreads();   // all reads done before next iter's loads land
    }

    // epilogue: C/D layout col=lane&15, row=(lane>>4)*4+reg  [m89-verified]
    float* Xs = Xp + (size_t)bz * BATCH * NOUT;
    const int rbase = bx * BM + wm * 64 + (lane >> 4) * 4;
    const int cbase = by * BN + wn * 64 + (lane & 15);
    #pragma unroll
    for (int mi = 0; mi < 4; ++mi)
        #pragma unroll
        for (int ni = 0; ni < 4; ++ni)
            #pragma unroll
            for (int rr = 0; rr < 4; ++rr) {
                int row = rbase + mi * 16 + rr;
                int col = cbase + ni * 16;
                Xs[(size_t)row * NOUT + col] = acc[mi][ni][rr];
            }
}

// ---------------------------------------------------------------------------
// out[b] = sum_d (sum_bz Xp[bz][b][d] + proj_b[d]) * ent[t[b], d]
// one wave per b; vectorized f32x4 path when inputs are f32
// ---------------------------------------------------------------------------
__global__ __launch_bounds__(256) void score_kernel(
    const int* __restrict__ t, const void* __restrict__ ent,
    const float* __restrict__ Xp, const void* __restrict__ projb,
    void* __restrict__ out)
{
    const int lane = threadIdx.x & 63;
    const int wave = threadIdx.x >> 6;
    const int b = blockIdx.x * 4 + wave;
    const int isf = sniff_isf32((const unsigned short*)ent);
    const size_t tb = (size_t)t[b] * DIM;
    float s = 0.f;
    if (isf) {
        const float* te = (const float*)ent + tb;
        const float* pb = (const float*)projb;
        const int d0 = lane * 8;
        #pragma unroll
        for (int jj = 0; jj < 2; ++jj) {
            int d = d0 + jj * 4;
            f32x4 xp = *(const f32x4*)(pb + d);
            #pragma unroll
            for (int z = 0; z < KSPLIT; ++z)
                xp += *(const f32x4*)(Xp + (size_t)z * BATCH * NOUT + (size_t)b * NOUT + d);
            f32x4 tv = *(const f32x4*)(te + d);
            s += xp[0]*tv[0] + xp[1]*tv[1] + xp[2]*tv[2] + xp[3]*tv[3];
        }
    } else {
        #pragma unroll
        for (int j = 0; j < 8; ++j) {
            int d = lane + 64 * j;
            float xp = ldv(projb, d, 0);
            #pragma unroll
            for (int z = 0; z < KSPLIT; ++z)
                xp += Xp[(size_t)z * BATCH * NOUT + (size_t)b * NOUT + d];
            s += xp * ldv(ent, tb + d, 0);
        }
    }
    #pragma unroll
    for (int o = 32; o; o >>= 1) s += __shfl_xor(s, o, 64);
    if (lane == 0) {
        if (isf) ((float*)out)[b] = s;
        else     ((unsigned short*)out)[b] = f2b(s);
    }
}

// ---------------------------------------------------------------------------
// MEASUREMENT ROUND: gemm_kernel launched 3x (idempotent). dur_us vs R5's
// 334.4 gives 2x the true GEMM duration: G = (dur - 334.4) / 2.
// ---------------------------------------------------------------------------
extern "C" void kernel_launch(void* const* d_in, const int* in_sizes, int n_in,
                              void* d_out, int out_size, void* d_ws, size_t ws_size,
                              hipStream_t stream)
{
    const int* h = (const int*)d_in[0];
    const int* r = (const int*)d_in[1];
    const int* t = (const int*)d_in[2];
    const void* ent    = d_in[3];
    const void* rel    = d_in[4];
    const void* conv_w = d_in[5];
    const void* conv_b = d_in[6];
    const void* projw  = d_in[7];
    const void* projb  = d_in[8];

    unsigned short* feat = (unsigned short*)d_ws;                         // 64 MiB
    unsigned short* pw16 = (unsigned short*)((char*)d_ws + (size_t)BATCH * KDIM * 2);
    float* Xp = (float*)((char*)pw16 + (size_t)PWN * 2);                  // KSPLIT x 4 MiB

    prep_kernel<<<CONVBLK + BATCH, 256, 0, stream>>>(h, r, ent, rel, conv_w, conv_b,
                                                     projw, pw16, feat);
    gemm_kernel<<<dim3(BATCH / BM, NOUT / BN, KSPLIT), 256, 0, stream>>>(feat, pw16, Xp);
    gemm_kernel<<<dim3(BATCH / BM, NOUT / BN, KSPLIT), 256, 0, stream>>>(feat, pw16, Xp);
    gemm_kernel<<<dim3(BATCH / BM, NOUT / BN, KSPLIT), 256, 0, stream>>>(feat, pw16, Xp);
    score_kernel<<<BATCH / 4, 256, 0, stream>>>(t, ent, Xp, projb, d_out);
}

// Round 9
// 333.792 us; speedup vs baseline: 1.2722x; 1.2722x over previous
//
#include <hip/hip_runtime.h>

#define DIM    512
#define CH     32
#define KDIM   16384   // CH*DIM
#define BATCH  2048
#define NOUT   512     // projection output dim
#define PWN    (NOUT * KDIM)   // proj_w elements: 8,388,608
#define CONVBLK (PWN / 4 / 256)  // 8192 blocks for the convert half

#define BM 128
#define BN 128
#define BK 64
#define KSPLIT 8
#define KC (KDIM / KSPLIT)   // 2048

typedef short bf16x8 __attribute__((ext_vector_type(8)));
typedef float f32x4  __attribute__((ext_vector_type(4)));

__device__ __forceinline__ float b2f(unsigned short u) {
    union { unsigned int i; float f; } v; v.i = ((unsigned int)u) << 16; return v.f;
}
__device__ __forceinline__ unsigned short f2b(float f) {
    union { float f; unsigned int i; } v; v.f = f;
    unsigned int r = v.i + 0x7fffu + ((v.i >> 16) & 1u);
    return (unsigned short)(r >> 16);
}
// dtype-flag load: isf=1 -> float32 array, isf=0 -> bf16 array
__device__ __forceinline__ float ldv(const void* p, size_t i, int isf) {
    return isf ? ((const float*)p)[i] : b2f(((const unsigned short*)p)[i]);
}
// In-wave dtype sniff on ent: f32 mantissa halfwords look random (~5% hit in
// the bf16-exponent window), bf16 halfwords land in it nearly always.
__device__ __forceinline__ int sniff_isf32(const unsigned short* ent_raw) {
    int lane = threadIdx.x & 63;
    unsigned short u = ent_raw[2 * lane];
    int eb = (u >> 8) & 0x7F;
    unsigned long long m = __ballot(eb >= 0x36 && eb < 0x3C);
    return (__popcll(m) < 32) ? 1 : 0;
}

__device__ __forceinline__ void gload_lds16(const unsigned short* g, unsigned short* l) {
    __builtin_amdgcn_global_load_lds(
        (const __attribute__((address_space(1))) void*)g,
        (__attribute__((address_space(3))) void*)l,
        16, 0, 0);
}

// ---------------------------------------------------------------------------
// Fused prep: blocks [0, CONVBLK) convert proj_w -> bf16 pw16;
// blocks [CONVBLK, CONVBLK+BATCH) build feat.
// feat[b, c*512+i] = relu(conv(concat(ent[h], rel[r]))[c, i] + cb[c]);
// SAME-pad k=3 cross-correlation truncated to i in [0,512): needs ent[h]
// (x[0..511]) and rel[r][0] (x[512]); left pad x[-1]=0.
// ---------------------------------------------------------------------------
__global__ __launch_bounds__(256) void prep_kernel(
    const int* __restrict__ h, const int* __restrict__ r,
    const void* __restrict__ ent, const void* __restrict__ rel,
    const void* __restrict__ conv_w, const void* __restrict__ conv_b,
    const void* __restrict__ projw,
    unsigned short* __restrict__ pw16, unsigned short* __restrict__ feat)
{
    const int tid = threadIdx.x;
    const int isf = sniff_isf32((const unsigned short*)ent);

    if (blockIdx.x < CONVBLK) {
        size_t i0 = ((size_t)blockIdx.x * 256 + tid) * 4;
        if (isf) {
            f32x4 v = *(const f32x4*)((const float*)projw + i0);
            unsigned int p0 = (unsigned int)f2b(v[0]) | ((unsigned int)f2b(v[1]) << 16);
            unsigned int p1 = (unsigned int)f2b(v[2]) | ((unsigned int)f2b(v[3]) << 16);
            *(unsigned int*)(pw16 + i0) = p0;
            *(unsigned int*)(pw16 + i0 + 2) = p1;
        } else {
            *(unsigned long long*)(pw16 + i0) =
                *(const unsigned long long*)((const unsigned short*)projw + i0);
        }
        return;
    }

    __shared__ float xs[DIM + 2];      // xs[0]=0 pad, xs[1..512]=h_e, xs[513]=r_e[0]
    __shared__ float wS[CH][4];
    const int b = blockIdx.x - CONVBLK;

    const size_t hb = (size_t)h[b] * DIM;
    for (int j = tid; j < DIM; j += 256) xs[1 + j] = ldv(ent, hb + j, isf);
    if (tid == 0) xs[0] = 0.0f;
    if (tid == 1) xs[DIM + 1] = ldv(rel, (size_t)r[b] * DIM, isf);
    if (tid >= 64 && tid < 96) {
        int c = tid - 64;
        wS[c][0] = ldv(conv_w, c * 3 + 0, isf);
        wS[c][1] = ldv(conv_w, c * 3 + 1, isf);
        wS[c][2] = ldv(conv_w, c * 3 + 2, isf);
        wS[c][3] = ldv(conv_b, c, isf);
    }
    __syncthreads();

    unsigned short* fb = feat + (size_t)b * KDIM;
    const int i0 = tid * 2;            // 2 adjacent outputs per channel
    float x0 = xs[i0], x1 = xs[i0 + 1], x2 = xs[i0 + 2], x3 = xs[i0 + 3];
    #pragma unroll 8
    for (int c = 0; c < CH; ++c) {
        float w0 = wS[c][0], w1 = wS[c][1], w2 = wS[c][2], cb = wS[c][3];
        float v0 = fmaxf(fmaf(w0, x0, fmaf(w1, x1, fmaf(w2, x2, cb))), 0.0f);
        float v1 = fmaxf(fmaf(w0, x1, fmaf(w1, x2, fmaf(w2, x3, cb))), 0.0f);
        unsigned int pack = (unsigned int)f2b(v0) | ((unsigned int)f2b(v1) << 16);
        *(unsigned int*)&fb[c * DIM + i0] = pack;
    }
}

// ---------------------------------------------------------------------------
// Xp[bz][m][n] = sum_{k slice bz} feat[m,k] * pw16[n,k]   (bf16 MFMA gemm_bt)
// M=2048 N=512 K=16384; 128x128 tile, BK=64, split-K=8 -> 512 blocks (2/CU).
// 45 us measured (R8 3x-launch calibration) = 764 TF ~ 87% of the
// m97-structure HIP-source plateau. Async global_load_lds width-16; LDS dst
// byte offset = 16*tid -> wave-uniform base + lane*16 (G-L-LDS rule).
// ---------------------------------------------------------------------------
__global__ __launch_bounds__(256, 2) void gemm_kernel(
    const unsigned short* __restrict__ feat,
    const unsigned short* __restrict__ pw16,
    float* __restrict__ Xp)
{
    __shared__ __align__(16) unsigned short As[BM * BK];   // 16 KB
    __shared__ __align__(16) unsigned short Bs[BN * BK];   // 16 KB

    const int tid  = threadIdx.x;
    const int lane = tid & 63;
    const int wave = tid >> 6;
    const int wm = wave & 1;         // 2x2 wave grid, each wave 64x64
    const int wn = wave >> 1;
    const int bx = blockIdx.x, by = blockIdx.y, bz = blockIdx.z;

    const unsigned short* Ab = feat + (size_t)(bx * BM) * KDIM + bz * KC;
    const unsigned short* Bb = pw16 + (size_t)(by * BN) * KDIM + bz * KC;

    const int row_ld = tid >> 3;         // 0..31
    const int koff   = (tid & 7) * 8;    // 8 bf16 = 16 B per lane

    const f32x4 zero = {0.f, 0.f, 0.f, 0.f};
    f32x4 acc[4][4];
    #pragma unroll
    for (int i = 0; i < 4; ++i)
        #pragma unroll
        for (int j = 0; j < 4; ++j) acc[i][j] = zero;

    const int fRow = lane & 15;          // operand row within 16
    const int fK   = (lane >> 4) * 8;    // k start within each 32-chunk

    for (int kk = 0; kk < KC; kk += BK) {
        #pragma unroll
        for (int j = 0; j < 4; ++j) {
            int rw = row_ld + 32 * j;
            gload_lds16(Ab + (size_t)rw * KDIM + kk + koff, As + rw * BK + koff);
            gload_lds16(Bb + (size_t)rw * KDIM + kk + koff, Bs + rw * BK + koff);
        }
        __syncthreads();   // drains vmcnt: staged data visible

        #pragma unroll
        for (int ko = 0; ko < 2; ++ko) {
            bf16x8 af[4], bfr[4];
            #pragma unroll
            for (int mi = 0; mi < 4; ++mi)
                af[mi] = *(const bf16x8*)&As[(wm * 64 + mi * 16 + fRow) * BK + ko * 32 + fK];
            #pragma unroll
            for (int ni = 0; ni < 4; ++ni)
                bfr[ni] = *(const bf16x8*)&Bs[(wn * 64 + ni * 16 + fRow) * BK + ko * 32 + fK];
            #pragma unroll
            for (int mi = 0; mi < 4; ++mi)
                #pragma unroll
                for (int ni = 0; ni < 4; ++ni)
                    acc[mi][ni] = __builtin_amdgcn_mfma_f32_16x16x32_bf16(
                        af[mi], bfr[ni], acc[mi][ni], 0, 0, 0);
        }
        __syncthreads();   // all reads done before next iter's loads land
    }

    // epilogue: C/D layout col=lane&15, row=(lane>>4)*4+reg  [m89-verified]
    float* Xs = Xp + (size_t)bz * BATCH * NOUT;
    const int rbase = bx * BM + wm * 64 + (lane >> 4) * 4;
    const int cbase = by * BN + wn * 64 + (lane & 15);
    #pragma unroll
    for (int mi = 0; mi < 4; ++mi)
        #pragma unroll
        for (int ni = 0; ni < 4; ++ni)
            #pragma unroll
            for (int rr = 0; rr < 4; ++rr) {
                int row = rbase + mi * 16 + rr;
                int col = cbase + ni * 16;
                Xs[(size_t)row * NOUT + col] = acc[mi][ni][rr];
            }
}

// ---------------------------------------------------------------------------
// out[b] = sum_d (sum_bz Xp[bz][b][d] + proj_b[d]) * ent[t[b], d]
// one wave per b; vectorized f32x4 path when inputs are f32
// ---------------------------------------------------------------------------
__global__ __launch_bounds__(256) void score_kernel(
    const int* __restrict__ t, const void* __restrict__ ent,
    const float* __restrict__ Xp, const void* __restrict__ projb,
    void* __restrict__ out)
{
    const int lane = threadIdx.x & 63;
    const int wave = threadIdx.x >> 6;
    const int b = blockIdx.x * 4 + wave;
    const int isf = sniff_isf32((const unsigned short*)ent);
    const size_t tb = (size_t)t[b] * DIM;
    float s = 0.f;
    if (isf) {
        const float* te = (const float*)ent + tb;
        const float* pb = (const float*)projb;
        const int d0 = lane * 8;
        #pragma unroll
        for (int jj = 0; jj < 2; ++jj) {
            int d = d0 + jj * 4;
            f32x4 xp = *(const f32x4*)(pb + d);
            #pragma unroll
            for (int z = 0; z < KSPLIT; ++z)
                xp += *(const f32x4*)(Xp + (size_t)z * BATCH * NOUT + (size_t)b * NOUT + d);
            f32x4 tv = *(const f32x4*)(te + d);
            s += xp[0]*tv[0] + xp[1]*tv[1] + xp[2]*tv[2] + xp[3]*tv[3];
        }
    } else {
        #pragma unroll
        for (int j = 0; j < 8; ++j) {
            int d = lane + 64 * j;
            float xp = ldv(projb, d, 0);
            #pragma unroll
            for (int z = 0; z < KSPLIT; ++z)
                xp += Xp[(size_t)z * BATCH * NOUT + (size_t)b * NOUT + d];
            s += xp * ldv(ent, tb + d, 0);
        }
    }
    #pragma unroll
    for (int o = 32; o; o >>= 1) s += __shfl_xor(s, o, 64);
    if (lane == 0) {
        if (isf) ((float*)out)[b] = s;
        else     ((unsigned short*)out)[b] = f2b(s);
    }
}

// ---------------------------------------------------------------------------
extern "C" void kernel_launch(void* const* d_in, const int* in_sizes, int n_in,
                              void* d_out, int out_size, void* d_ws, size_t ws_size,
                              hipStream_t stream)
{
    const int* h = (const int*)d_in[0];
    const int* r = (const int*)d_in[1];
    const int* t = (const int*)d_in[2];
    const void* ent    = d_in[3];
    const void* rel    = d_in[4];
    const void* conv_w = d_in[5];
    const void* conv_b = d_in[6];
    const void* projw  = d_in[7];
    const void* projb  = d_in[8];

    unsigned short* feat = (unsigned short*)d_ws;                         // 64 MiB
    unsigned short* pw16 = (unsigned short*)((char*)d_ws + (size_t)BATCH * KDIM * 2);
    float* Xp = (float*)((char*)pw16 + (size_t)PWN * 2);                  // KSPLIT x 4 MiB

    prep_kernel<<<CONVBLK + BATCH, 256, 0, stream>>>(h, r, ent, rel, conv_w, conv_b,
                                                     projw, pw16, feat);
    gemm_kernel<<<dim3(BATCH / BM, NOUT / BN, KSPLIT), 256, 0, stream>>>(feat, pw16, Xp);
    score_kernel<<<BATCH / 4, 256, 0, stream>>>(t, ent, Xp, projb, d_out);
}